// Round 1
// baseline (1630.827 us; speedup 1.0000x reference)
//
#include <hip/hip_runtime.h>
#include <stdint.h>

// ---------------------------------------------------------------------------
// Enc_block: KNN graph + gumbel-softmax soft edges + PointTransformerConv +
// down + neighbor max-pool + GridSampling.  N=8192, Cin=64, Cout=128, K=16.
// ---------------------------------------------------------------------------

#define PARTITIONABLE 1   // JAX >= 0.5: threefry_partitionable default True

typedef unsigned int u32;

#define NN 8192
#define EPS20 1e-20f

// ---------------- threefry2x32 (JAX key schedule) ----------------
__host__ __device__ static inline u32 rotl32(u32 v, int r){ return (v<<r)|(v>>(32-r)); }

__host__ __device__ static inline void tf2x32(u32 k0, u32 k1, u32 c0, u32 c1, u32& o0, u32& o1){
  u32 ks2 = k0 ^ k1 ^ 0x1BD11BDAu;
  u32 x0 = c0 + k0;
  u32 x1 = c1 + k1;
#define TFR(r) x0 += x1; x1 = rotl32(x1,(r)); x1 ^= x0;
  TFR(13) TFR(15) TFR(26) TFR(6)
  x0 += k1;  x1 += ks2 + 1u;
  TFR(17) TFR(29) TFR(16) TFR(24)
  x0 += ks2; x1 += k0 + 2u;
  TFR(13) TFR(15) TFR(26) TFR(6)
  x0 += k0;  x1 += k1 + 3u;
  TFR(17) TFR(29) TFR(16) TFR(24)
  x0 += k1;  x1 += ks2 + 4u;
  TFR(13) TFR(15) TFR(26) TFR(6)
  x0 += ks2; x1 += k0 + 5u;
#undef TFR
  o0 = x0; o1 = x1;
}

__device__ static inline u32 rbits(u32 k0, u32 k1, u32 idx, u32 total){
#if PARTITIONABLE
  (void)total;
  u32 o0,o1; tf2x32(k0,k1, 0u, idx, o0,o1);   // 64-bit counter (0, idx)
  return o0 ^ o1;                              // 32-bit fold
#else
  u32 half = total >> 1;
  u32 lane = idx < half ? idx : idx - half;
  u32 o0,o1; tf2x32(k0,k1, lane, lane+half, o0,o1);
  return idx < half ? o0 : o1;
#endif
}

__device__ static inline float u01(u32 b){
  return __uint_as_float((b>>9) | 0x3f800000u) - 1.0f;   // [0,1), JAX formula
}

// z = (log(exp(-d2)+eps) + gumbel(u)) / TEMP, TEMP=0.5 (exact *2)
__device__ static inline float z_val(const float* ei, float sei, const float* ej, float sej, u32 ub){
  float dot = 0.0f;
  #pragma unroll
  for (int d=0; d<10; d++) dot += ei[d]*ej[d];
  float d2 = fmaxf(sei + sej - 2.0f*dot, 0.0f);
  float u = u01(ub);
  float g = -logf(-logf(u + EPS20) + EPS20);
  return 2.0f*(logf(expf(-d2) + EPS20) + g);
}

// ---------------- workspace layout ----------------
static constexpr size_t OFF_EMBT = 0;                         // [10][8192] f32 (transposed emb)
static constexpr size_t OFF_SE   = OFF_EMBT + (size_t)10*8192*4;
static constexpr size_t OFF_SP   = OFF_SE   + (size_t)8192*4;
static constexpr size_t OFF_CMAX = OFF_SP   + (size_t)8192*4;
static constexpr size_t OFF_CSUM = OFF_CMAX + (size_t)8192*4;
static constexpr size_t OFF_PMAX = OFF_CSUM + (size_t)8192*4;  // [32][8192]
static constexpr size_t OFF_PSUM = OFF_PMAX + (size_t)32*8192*4;
static constexpr size_t OFF_SSRC = OFF_PSUM + (size_t)32*8192*4; // int [8192][16]
static constexpr size_t OFF_TOPV = OFF_SSRC + (size_t)8192*16*4;
static constexpr size_t OFF_KSRC = OFF_TOPV + (size_t)8192*16*4; // int [8192][16]
static constexpr size_t OFF_A    = OFF_KSRC + (size_t)8192*16*4; // x@Wsrc
static constexpr size_t OFF_B    = OFF_A    + (size_t)8192*128*4; // x@Wdst
static constexpr size_t OFF_V    = OFF_B    + (size_t)8192*128*4; // x@Wlin
static constexpr size_t OFF_H    = OFF_V    + (size_t)8192*128*4; // conv out
static constexpr size_t OFF_HD   = OFF_H    + (size_t)8192*128*4; // after down
static constexpr size_t OFF_Y    = OFF_HD   + (size_t)8192*128*4; // after pool
static constexpr size_t OFF_ACCX = OFF_Y    + (size_t)8192*128*4; // voxel sums
static constexpr size_t OFF_ACCP = OFF_ACCX + (size_t)8192*128*4; // voxel pos sums
static constexpr size_t OFF_HIST = OFF_ACCP + (size_t)8192*3*4;   // int [8192]
static constexpr size_t OFF_RANK = OFF_HIST + (size_t)8192*4;     // int [8192]
static constexpr size_t OFF_UCNT = OFF_RANK + (size_t)8192*4;     // int [8192]
static constexpr size_t OFF_VID  = OFF_UCNT + (size_t)8192*4;     // int [8192]
static constexpr size_t OFF_META = OFF_VID  + (size_t)8192*4;     // posmin f[3] @0, nv i[3] @16B, U i @32B

// ---------------- kernels ----------------

// pos column-min and voxel-grid extents
__global__ __launch_bounds__(256) void k_prep(const float* __restrict__ pos,
                                              float* __restrict__ meta_f, int* __restrict__ meta_i){
  __shared__ float red[256][3];
  __shared__ int   redi[256][3];
  __shared__ float pmn[3];
  int t = threadIdx.x;
  float mn[3] = {1e30f,1e30f,1e30f};
  for (int n=t; n<NN; n+=256){
    #pragma unroll
    for (int d=0; d<3; d++) mn[d] = fminf(mn[d], pos[n*3+d]);
  }
  #pragma unroll
  for (int d=0; d<3; d++) red[t][d] = mn[d];
  __syncthreads();
  for (int s=128; s>0; s>>=1){
    if (t < s){ for (int d=0; d<3; d++) red[t][d] = fminf(red[t][d], red[t+s][d]); }
    __syncthreads();
  }
  if (t < 3) pmn[t] = red[0][t];
  __syncthreads();
  int mx[3] = {0,0,0};
  for (int n=t; n<NN; n+=256){
    #pragma unroll
    for (int d=0; d<3; d++){
      int v = (int)floorf((pos[n*3+d] - pmn[d]) * 2.0f);   // /0.5 == *2 exactly
      mx[d] = max(mx[d], v);
    }
  }
  #pragma unroll
  for (int d=0; d<3; d++) redi[t][d] = mx[d];
  __syncthreads();
  for (int s=128; s>0; s>>=1){
    if (t < s){ for (int d=0; d<3; d++) redi[t][d] = max(redi[t][d], redi[t+s][d]); }
    __syncthreads();
  }
  if (t == 0){
    meta_f[0]=pmn[0]; meta_f[1]=pmn[1]; meta_f[2]=pmn[2];
    meta_i[0]=redi[0][0]+1; meta_i[1]=redi[0][1]+1; meta_i[2]=redi[0][2]+1;
  }
}

// voxel id + histogram + pos squared norms
__global__ __launch_bounds__(256) void k_vid(const float* __restrict__ pos,
                                             const float* __restrict__ meta_f, const int* __restrict__ meta_i,
                                             int* __restrict__ vid, int* __restrict__ hist,
                                             float* __restrict__ sp){
  int n = blockIdx.x*256 + threadIdx.x;
  float p0=pos[n*3], p1=pos[n*3+1], p2=pos[n*3+2];
  sp[n] = p0*p0 + p1*p1 + p2*p2;
  int v0 = (int)floorf((p0-meta_f[0])*2.0f);
  int v1 = (int)floorf((p1-meta_f[1])*2.0f);
  int v2 = (int)floorf((p2-meta_f[2])*2.0f);
  int id = (v0*meta_i[1] + v1)*meta_i[2] + v2;
  vid[n] = id;
  atomicAdd(&hist[id], 1);
}

// emb = relu(x@Wg1+bg1)@Wg2+bg2 + u*0.001 ; se = |emb|^2 ; embT[10][N]
__global__ __launch_bounds__(64) void k_emb(const float* __restrict__ x,
    const float* __restrict__ Wg1, const float* __restrict__ bg1,
    const float* __restrict__ Wg2, const float* __restrict__ bg2,
    u32 ka, u32 kb, float* __restrict__ embT, float* __restrict__ se){
  int i = blockIdx.x; int t = threadIdx.x;
  __shared__ float xs[64], hs[64], esq[10];
  xs[t] = x[i*64+t];
  __syncthreads();
  float a = bg1[t];
  for (int k=0; k<64; k++) a += xs[k]*Wg1[k*64+t];
  hs[t] = fmaxf(a, 0.0f);
  __syncthreads();
  if (t < 10){
    float e = bg2[t];
    for (int k=0; k<64; k++) e += hs[k]*Wg2[k*10+t];
    e += u01(rbits(ka, kb, (u32)(i*10+t), 81920u)) * 0.001f;
    embT[t*NN + i] = e;
    esq[t] = e*e;
  }
  __syncthreads();
  if (t == 0){
    float ssum = 0.0f;
    #pragma unroll
    for (int d=0; d<10; d++) ssum += esq[d];
    se[i] = ssum;
  }
}

// KNN: top-16 smallest d2 per row (diag excluded), ties -> lower index
__global__ __launch_bounds__(64) void k_knn(const float* __restrict__ pos, const float* __restrict__ sp,
                                            int* __restrict__ knn_src){
  int i = blockIdx.x; int l = threadIdx.x;
  float pi0=pos[i*3], pi1=pos[i*3+1], pi2=pos[i*3+2];
  float spi = sp[i];
  float lv[16]; int lj[16];
  #pragma unroll
  for (int s=0; s<16; s++){ lv[s]=1e30f; lj[s]=0x7fffffff; }
  for (int tt=0; tt<128; tt++){
    int j = l + 64*tt;
    if (j == i) continue;
    float d = spi + sp[j] - 2.0f*(pi0*pos[j*3] + pi1*pos[j*3+1] + pi2*pos[j*3+2]);
    d = fmaxf(d, 0.0f);
    if (d < lv[15]){
      lv[15]=d; lj[15]=j;
      #pragma unroll
      for (int s=15; s>0; s--){
        if (lv[s] < lv[s-1]){ float tv=lv[s]; lv[s]=lv[s-1]; lv[s-1]=tv; int tj=lj[s]; lj[s]=lj[s-1]; lj[s-1]=tj; }
      }
    }
  }
  for (int r=0; r<16; r++){
    float bv = lv[0]; int bj = lj[0];
    #pragma unroll
    for (int off=32; off>=1; off>>=1){
      float ov = __shfl_xor(bv, off);
      int   oj = __shfl_xor(bj, off);
      if (ov < bv || (ov == bv && oj < bj)){ bv = ov; bj = oj; }
    }
    if (l == 0) knn_src[i*16+r] = bj;
    if (lj[0] == bj){
      #pragma unroll
      for (int s=0; s<15; s++){ lv[s]=lv[s+1]; lj[s]=lj[s+1]; }
      lv[15]=1e30f; lj[15]=0x7fffffff;
    }
  }
}

// column softmax stats over a 256-row chunk (online max/sum)
__global__ __launch_bounds__(256) void k_colstats(const float* __restrict__ embT, const float* __restrict__ se,
                                                  u32 ka, u32 kb,
                                                  float* __restrict__ pmax, float* __restrict__ psum){
  __shared__ float eS[256][10];
  __shared__ float sS[256];
  int t = threadIdx.x;
  int j = blockIdx.x*256 + t;
  int i0 = blockIdx.y*256;
  for (int idx=t; idx<2560; idx+=256){
    int d = idx >> 8;         // /256
    int r = idx & 255;
    eS[r][d] = embT[d*NN + i0 + r];
  }
  sS[t] = se[i0 + t];
  __syncthreads();
  float ej[10];
  #pragma unroll
  for (int d=0; d<10; d++) ej[d] = embT[d*NN + j];
  float sej = se[j];
  float m = -1e30f, s = 0.0f;
  for (int r=0; r<256; r++){
    u32 p = (u32)(i0+r)*8192u + (u32)j;
    float z = z_val(eS[r], sS[r], ej, sej, rbits(ka, kb, p, 67108864u));
    if (z > m){ s = s*expf(m - z) + 1.0f; m = z; }
    else      { s += expf(z - m); }
  }
  pmax[blockIdx.y*NN + j] = m;
  psum[blockIdx.y*NN + j] = s;
}

__global__ __launch_bounds__(256) void k_colcombine(const float* __restrict__ pmax, const float* __restrict__ psum,
                                                    float* __restrict__ colmax, float* __restrict__ colsum){
  int j = blockIdx.x*256 + threadIdx.x;
  float M = -1e30f;
  for (int c=0; c<32; c++) M = fmaxf(M, pmax[c*NN + j]);
  float S = 0.0f;
  for (int c=0; c<32; c++) S += psum[c*NN + j] * expf(pmax[c*NN + j] - M);
  colmax[j] = M; colsum[j] = S;
}

// per-row top-16 of probs = exp(z - colmax[j]) / colsum[j]
__global__ __launch_bounds__(64) void k_rowtopk(const float* __restrict__ embT, const float* __restrict__ se,
    const float* __restrict__ colmax, const float* __restrict__ colsum,
    u32 ka, u32 kb, int* __restrict__ soft_src, float* __restrict__ top_v){
  int i = blockIdx.x; int l = threadIdx.x;
  float ei[10];
  #pragma unroll
  for (int d=0; d<10; d++) ei[d] = embT[d*NN + i];
  float sei = se[i];
  float lv[16]; int lj[16];
  #pragma unroll
  for (int s=0; s<16; s++){ lv[s]=-1e30f; lj[s]=0x7fffffff; }
  for (int tt=0; tt<128; tt++){
    int j = l + 64*tt;
    float ej[10];
    #pragma unroll
    for (int d=0; d<10; d++) ej[d] = embT[d*NN + j];
    u32 p = (u32)i*8192u + (u32)j;
    float z = z_val(ei, sei, ej, se[j], rbits(ka, kb, p, 67108864u));
    float pr = expf(z - colmax[j]) / colsum[j];
    if (pr > lv[15]){
      lv[15]=pr; lj[15]=j;
      #pragma unroll
      for (int s=15; s>0; s--){
        if (lv[s] > lv[s-1]){ float tv=lv[s]; lv[s]=lv[s-1]; lv[s-1]=tv; int tj=lj[s]; lj[s]=lj[s-1]; lj[s-1]=tj; }
      }
    }
  }
  for (int r=0; r<16; r++){
    float bv = lv[0]; int bj = lj[0];
    #pragma unroll
    for (int off=32; off>=1; off>>=1){
      float ov = __shfl_xor(bv, off);
      int   oj = __shfl_xor(bj, off);
      if (ov > bv || (ov == bv && oj < bj)){ bv = ov; bj = oj; }
    }
    if (l == 0){ soft_src[i*16+r] = bj; top_v[i*16+r] = bv; }
    if (lj[0] == bj){
      #pragma unroll
      for (int s=0; s<15; s++){ lv[s]=lv[s+1]; lj[s]=lj[s+1]; }
      lv[15]=-1e30f; lj[15]=0x7fffffff;
    }
  }
}

// A = x@Wsrc, B = x@Wdst, V = x@Wlin  (8 rows per block)
__global__ __launch_bounds__(128) void k_xw(const float* __restrict__ x,
    const float* __restrict__ Wsrc, const float* __restrict__ Wdst, const float* __restrict__ Wlin,
    float* __restrict__ A, float* __restrict__ B, float* __restrict__ V){
  int g0 = blockIdx.x*8; int c = threadIdx.x;
  __shared__ float xs[8][64];
  for (int idx=c; idx<512; idx+=128) xs[idx>>6][idx&63] = x[(g0 + (idx>>6))*64 + (idx&63)];
  __syncthreads();
  float aA[8], aB[8], aV[8];
  #pragma unroll
  for (int g=0; g<8; g++){ aA[g]=0.0f; aB[g]=0.0f; aV[g]=0.0f; }
  for (int k=0; k<64; k++){
    float ws=Wsrc[k*128+c], wd=Wdst[k*128+c], wl=Wlin[k*128+c];
    #pragma unroll
    for (int g=0; g<8; g++){
      float xv = xs[g][k];
      aA[g] += xv*ws; aB[g] += xv*wd; aV[g] += xv*wl;
    }
  }
  #pragma unroll
  for (int g=0; g<8; g++){
    A[(g0+g)*128+c]=aA[g]; B[(g0+g)*128+c]=aB[g]; V[(g0+g)*128+c]=aV[g];
  }
}

#define GEMM32(WPTR, BIASVAL)                                              \
  {                                                                        \
    _Pragma("unroll")                                                      \
    for (int e=0; e<32; e++) acc[e] = (BIASVAL);                           \
    for (int k=0; k<128; k+=4){                                            \
      float w0=(WPTR)[(k+0)*128+c], w1=(WPTR)[(k+1)*128+c];                \
      float w2=(WPTR)[(k+2)*128+c], w3=(WPTR)[(k+3)*128+c];                \
      _Pragma("unroll")                                                    \
      for (int e=0; e<32; e++){                                            \
        const float4 ev = *(const float4*)(&ein[e][k]);                    \
        acc[e] += ev.x*w0 + ev.y*w1 + ev.z*w2 + ev.w*w3;                   \
      }                                                                    \
    }                                                                      \
  }

// PointTransformerConv: per-target fused (32 edges), vector attention
__global__ __launch_bounds__(128) void k_edge(const float* __restrict__ pos,
    const int* __restrict__ soft_src, const float* __restrict__ top_v, const int* __restrict__ knn_src,
    const float* __restrict__ A, const float* __restrict__ B, const float* __restrict__ V,
    const float* __restrict__ Wp1, const float* __restrict__ bp1,
    const float* __restrict__ Wp2, const float* __restrict__ bp2,
    const float* __restrict__ Wa1, const float* __restrict__ ba1,
    const float* __restrict__ Wa2, const float* __restrict__ ba2,
    float* __restrict__ h){
  int i = blockIdx.x; int c = threadIdx.x;
  __shared__ float ein[32][128];
  __shared__ int   ssrc[32];
  __shared__ float sw[32];
  __shared__ float sdp[32][3];
  if (c < 32){
    int s; float w;
    if (c < 16){ s = soft_src[i*16+c]; w = top_v[i*16+c]; }
    else       { s = knn_src[i*16+(c-16)]; w = 1.0f; }
    ssrc[c]=s; sw[c]=w;
    sdp[c][0]=pos[i*3]-pos[s*3]; sdp[c][1]=pos[i*3+1]-pos[s*3+1]; sdp[c][2]=pos[i*3+2]-pos[s*3+2];
  }
  __syncthreads();
  // ph = relu(dpos @ Wp1 + bp1)
  float w0=Wp1[c], w1=Wp1[128+c], w2=Wp1[256+c], b1=bp1[c];
  #pragma unroll
  for (int e=0; e<32; e++)
    ein[e][c] = fmaxf(sdp[e][0]*w0 + sdp[e][1]*w1 + sdp[e][2]*w2 + b1, 0.0f);
  __syncthreads();
  float acc[32];
  // delta = ph @ Wp2 + bp2
  GEMM32(Wp2, bp2[c]);
  __syncthreads();
  float dl[32];
  #pragma unroll
  for (int e=0; e<32; e++) dl[e] = acc[e];
  // q = B[i] - A[src] + delta
  float bi = B[i*128+c];
  #pragma unroll
  for (int e=0; e<32; e++) ein[e][c] = bi - A[ssrc[e]*128+c] + dl[e];
  __syncthreads();
  // ah = relu(q @ Wa1 + ba1)
  GEMM32(Wa1, ba1[c]);
  __syncthreads();
  #pragma unroll
  for (int e=0; e<32; e++) ein[e][c] = fmaxf(acc[e], 0.0f);
  __syncthreads();
  // logits = ah @ Wa2 + ba2
  GEMM32(Wa2, ba2[c]);
  // per-channel softmax over 32 edges, aggregate msg = attn*(V[src]+delta)*w
  float m = acc[0];
  #pragma unroll
  for (int e=1; e<32; e++) m = fmaxf(m, acc[e]);
  float ssum = 0.0f, hv = 0.0f;
  #pragma unroll
  for (int e=0; e<32; e++){
    float pe = expf(acc[e] - m);
    ssum += pe;
    hv += pe * (V[ssrc[e]*128+c] + dl[e]) * sw[e];
  }
  h[i*128+c] = hv / (ssum + 1e-16f);
}

// hd = relu(h @ Wd + bd)
__global__ __launch_bounds__(128) void k_down(const float* __restrict__ h,
    const float* __restrict__ Wd, const float* __restrict__ bd, float* __restrict__ hd){
  int g0 = blockIdx.x*8; int c = threadIdx.x;
  __shared__ float hs[8][128];
  for (int idx=c; idx<1024; idx+=128) hs[idx>>7][idx&127] = h[(g0 + (idx>>7))*128 + (idx&127)];
  __syncthreads();
  float acc[8]; float b = bd[c];
  #pragma unroll
  for (int g=0; g<8; g++) acc[g] = b;
  for (int k=0; k<128; k+=4){
    float w0=Wd[(k+0)*128+c], w1=Wd[(k+1)*128+c], w2=Wd[(k+2)*128+c], w3=Wd[(k+3)*128+c];
    #pragma unroll
    for (int g=0; g<8; g++){
      const float4 ev = *(const float4*)(&hs[g][k]);
      acc[g] += ev.x*w0 + ev.y*w1 + ev.z*w2 + ev.w*w3;
    }
  }
  #pragma unroll
  for (int g=0; g<8; g++) hd[(g0+g)*128+c] = fmaxf(acc[g], 0.0f);
}

// y = max(hd[i], max over 32 neighbors hd[src])
__global__ __launch_bounds__(128) void k_pool(const float* __restrict__ hd,
    const int* __restrict__ soft_src, const int* __restrict__ knn_src, float* __restrict__ y){
  int i = blockIdx.x; int c = threadIdx.x;
  __shared__ int ss[32];
  if (c < 16) ss[c] = soft_src[i*16+c];
  else if (c < 32) ss[c] = knn_src[i*16+(c-16)];
  __syncthreads();
  float p = hd[i*128+c];
  for (int e=0; e<32; e++) p = fmaxf(p, hd[ss[e]*128+c]);
  y[i*128+c] = p;
}

// ranks = sorted-unique inverse (count of nonzero bins with smaller vid)
__global__ __launch_bounds__(256) void k_scan(const int* __restrict__ hist,
    int* __restrict__ rank, int* __restrict__ ucnt, int* __restrict__ Uo){
  __shared__ int part[256];
  int t = threadIdx.x;
  int base = t*32;
  int cnt = 0;
  for (int b=0; b<32; b++) cnt += (hist[base+b] > 0);
  part[t] = cnt;
  __syncthreads();
  if (t == 0){
    int run = 0;
    for (int q=0; q<256; q++){ int v = part[q]; part[q] = run; run += v; }
    Uo[0] = run;
  }
  __syncthreads();
  int run = part[t];
  for (int b=0; b<32; b++){
    int bin = base + b;
    rank[bin] = run;
    int hv = hist[bin];
    if (hv > 0){ ucnt[run] = hv; run++; }
  }
}

__global__ __launch_bounds__(128) void k_agg(const float* __restrict__ y, const float* __restrict__ pos,
    const int* __restrict__ vid, const int* __restrict__ rank,
    float* __restrict__ accx, float* __restrict__ accp){
  int n = blockIdx.x; int c = threadIdx.x;
  int r = rank[vid[n]];
  atomicAdd(&accx[r*128+c], y[n*128+c]);
  if (c < 3) atomicAdd(&accp[r*3+c], pos[n*3+c]);
}

__global__ __launch_bounds__(128) void k_final(const float* __restrict__ accx, const float* __restrict__ accp,
    const int* __restrict__ ucnt, const int* __restrict__ Uo, float* __restrict__ out){
  int r = blockIdx.x; int c = threadIdx.x;
  int u = Uo[0];
  float cnt = (r < u) ? (float)ucnt[r] : 0.0f;
  float den = fmaxf(cnt, 1.0f);
  out[r*128+c] = (r < u) ? accx[r*128+c]/den : 0.0f;
  if (c < 3) out[(size_t)NN*128 + r*3 + c] = (r < u) ? accp[r*3+c]/den : 0.0f;
  if (c == 0) out[(size_t)NN*128 + (size_t)NN*3 + r] = cnt;
}

// ---------------- launcher ----------------
extern "C" void kernel_launch(void* const* d_in, const int* in_sizes, int n_in,
                              void* d_out, int out_size, void* d_ws, size_t ws_size,
                              hipStream_t stream){
  (void)in_sizes; (void)n_in; (void)out_size; (void)ws_size;
  const float* x    = (const float*)d_in[0];
  const float* pos  = (const float*)d_in[1];
  const float* Wg1  = (const float*)d_in[2];
  const float* bg1  = (const float*)d_in[3];
  const float* Wg2  = (const float*)d_in[4];
  const float* bg2  = (const float*)d_in[5];
  const float* Wlin = (const float*)d_in[6];
  const float* Wsrc = (const float*)d_in[7];
  const float* Wdst = (const float*)d_in[8];
  const float* Wp1  = (const float*)d_in[9];
  const float* bp1  = (const float*)d_in[10];
  const float* Wp2  = (const float*)d_in[11];
  const float* bp2  = (const float*)d_in[12];
  const float* Wa1  = (const float*)d_in[13];
  const float* ba1  = (const float*)d_in[14];
  const float* Wa2  = (const float*)d_in[15];
  const float* ba2  = (const float*)d_in[16];
  const float* Wd   = (const float*)d_in[17];
  const float* bd   = (const float*)d_in[18];

  char* ws = (char*)d_ws;
  float* embT   = (float*)(ws + OFF_EMBT);
  float* se     = (float*)(ws + OFF_SE);
  float* sp     = (float*)(ws + OFF_SP);
  float* colmax = (float*)(ws + OFF_CMAX);
  float* colsum = (float*)(ws + OFF_CSUM);
  float* pmax   = (float*)(ws + OFF_PMAX);
  float* psum   = (float*)(ws + OFF_PSUM);
  int*   ssrc   = (int*)  (ws + OFF_SSRC);
  float* topv   = (float*)(ws + OFF_TOPV);
  int*   ksrc   = (int*)  (ws + OFF_KSRC);
  float* A      = (float*)(ws + OFF_A);
  float* B      = (float*)(ws + OFF_B);
  float* V      = (float*)(ws + OFF_V);
  float* h      = (float*)(ws + OFF_H);
  float* hd     = (float*)(ws + OFF_HD);
  float* y      = (float*)(ws + OFF_Y);
  float* accx   = (float*)(ws + OFF_ACCX);
  float* accp   = (float*)(ws + OFF_ACCP);
  int*   hist   = (int*)  (ws + OFF_HIST);
  int*   rank   = (int*)  (ws + OFF_RANK);
  int*   ucnt   = (int*)  (ws + OFF_UCNT);
  int*   vid    = (int*)  (ws + OFF_VID);
  float* meta_f = (float*)(ws + OFF_META);
  int*   meta_i = (int*)  (ws + OFF_META + 16);
  int*   Uo     = (int*)  (ws + OFF_META + 32);

  // rk = jax.random.split(jax.random.key(42), 2)  -- host threefry
  u32 rk0a, rk0b, rk1a, rk1b;
#if PARTITIONABLE
  tf2x32(0u, 42u, 0u, 0u, rk0a, rk0b);   // foldlike split: key_j = threefry(key, (0, j))
  tf2x32(0u, 42u, 0u, 1u, rk1a, rk1b);
#else
  { u32 l0o0,l0o1,l1o0,l1o1;
    tf2x32(0u,42u, 0u,2u, l0o0,l0o1);
    tf2x32(0u,42u, 1u,3u, l1o0,l1o1);
    rk0a=l0o0; rk0b=l1o0; rk1a=l0o1; rk1b=l1o1; }
#endif

  hipMemsetAsync(hist, 0, 8192*4, stream);
  hipMemsetAsync(accx, 0, (size_t)8192*128*4, stream);
  hipMemsetAsync(accp, 0, (size_t)8192*3*4, stream);

  k_prep<<<1, 256, 0, stream>>>(pos, meta_f, meta_i);
  k_vid<<<32, 256, 0, stream>>>(pos, meta_f, meta_i, vid, hist, sp);
  k_emb<<<8192, 64, 0, stream>>>(x, Wg1, bg1, Wg2, bg2, rk0a, rk0b, embT, se);
  k_knn<<<8192, 64, 0, stream>>>(pos, sp, ksrc);
  k_colstats<<<dim3(32,32), 256, 0, stream>>>(embT, se, rk1a, rk1b, pmax, psum);
  k_colcombine<<<32, 256, 0, stream>>>(pmax, psum, colmax, colsum);
  k_rowtopk<<<8192, 64, 0, stream>>>(embT, se, colmax, colsum, rk1a, rk1b, ssrc, topv);
  k_xw<<<1024, 128, 0, stream>>>(x, Wsrc, Wdst, Wlin, A, B, V);
  k_edge<<<8192, 128, 0, stream>>>(pos, ssrc, topv, ksrc, A, B, V,
                                   Wp1, bp1, Wp2, bp2, Wa1, ba1, Wa2, ba2, h);
  k_down<<<1024, 128, 0, stream>>>(h, Wd, bd, hd);
  k_pool<<<8192, 128, 0, stream>>>(hd, ssrc, ksrc, y);
  k_scan<<<1, 256, 0, stream>>>(hist, rank, ucnt, Uo);
  k_agg<<<8192, 128, 0, stream>>>(y, pos, vid, rank, accx, accp);
  k_final<<<8192, 128, 0, stream>>>(accx, accp, ucnt, Uo, (float*)d_out);
}

// Round 2
// 1478.992 us; speedup vs baseline: 1.1027x; 1.1027x over previous
//
#include <hip/hip_runtime.h>
#include <stdint.h>

// ---------------------------------------------------------------------------
// Enc_block: KNN graph + gumbel-softmax soft edges + PointTransformerConv +
// down + neighbor max-pool + GridSampling.  N=8192, Cin=64, Cout=128, K=16.
// ---------------------------------------------------------------------------

#define PARTITIONABLE 1   // JAX >= 0.5: threefry_partitionable default True

typedef unsigned int u32;

#define NN 8192
#define EPS20 1e-20f

// ---------------- threefry2x32 (JAX key schedule) ----------------
__host__ __device__ static inline u32 rotl32(u32 v, int r){ return (v<<r)|(v>>(32-r)); }

__host__ __device__ static inline void tf2x32(u32 k0, u32 k1, u32 c0, u32 c1, u32& o0, u32& o1){
  u32 ks2 = k0 ^ k1 ^ 0x1BD11BDAu;
  u32 x0 = c0 + k0;
  u32 x1 = c1 + k1;
#define TFR(r) x0 += x1; x1 = rotl32(x1,(r)); x1 ^= x0;
  TFR(13) TFR(15) TFR(26) TFR(6)
  x0 += k1;  x1 += ks2 + 1u;
  TFR(17) TFR(29) TFR(16) TFR(24)
  x0 += ks2; x1 += k0 + 2u;
  TFR(13) TFR(15) TFR(26) TFR(6)
  x0 += k0;  x1 += k1 + 3u;
  TFR(17) TFR(29) TFR(16) TFR(24)
  x0 += k1;  x1 += ks2 + 4u;
  TFR(13) TFR(15) TFR(26) TFR(6)
  x0 += ks2; x1 += k0 + 5u;
#undef TFR
  o0 = x0; o1 = x1;
}

__device__ static inline u32 rbits(u32 k0, u32 k1, u32 idx, u32 total){
#if PARTITIONABLE
  (void)total;
  u32 o0,o1; tf2x32(k0,k1, 0u, idx, o0,o1);   // 64-bit counter (0, idx)
  return o0 ^ o1;                              // 32-bit fold
#else
  u32 half = total >> 1;
  u32 lane = idx < half ? idx : idx - half;
  u32 o0,o1; tf2x32(k0,k1, lane, lane+half, o0,o1);
  return idx < half ? o0 : o1;
#endif
}

__device__ static inline float u01(u32 b){
  return __uint_as_float((b>>9) | 0x3f800000u) - 1.0f;   // [0,1), JAX formula
}

// z = (log(exp(-d2)+eps) + gumbel(u)) / TEMP, TEMP=0.5 (exact *2)
// fast hardware transcendentals: ~1e-7 rel err, far below gumbel rank gaps
__device__ static inline float z_val(const float* ei, float sei, const float* ej, float sej, u32 ub){
  float dot = 0.0f;
  #pragma unroll
  for (int d=0; d<10; d++) dot += ei[d]*ej[d];
  float d2 = fmaxf(sei + sej - 2.0f*dot, 0.0f);
  float u = u01(ub);
  float g = -__logf(-__logf(u + EPS20) + EPS20);
  return 2.0f*(__logf(__expf(-d2) + EPS20) + g);
}

// ---------------- workspace layout ----------------
static constexpr size_t OFF_EMBT = 0;                         // [10][8192] f32 (transposed emb)
static constexpr size_t OFF_SE   = OFF_EMBT + (size_t)10*8192*4;
static constexpr size_t OFF_SP   = OFF_SE   + (size_t)8192*4;
static constexpr size_t OFF_CMAX = OFF_SP   + (size_t)8192*4;
static constexpr size_t OFF_CSUM = OFF_CMAX + (size_t)8192*4;
static constexpr size_t OFF_PMAX = OFF_CSUM + (size_t)8192*4;  // [32][8192]
static constexpr size_t OFF_PSUM = OFF_PMAX + (size_t)32*8192*4;
static constexpr size_t OFF_SSRC = OFF_PSUM + (size_t)32*8192*4; // int [8192][16]
static constexpr size_t OFF_TOPV = OFF_SSRC + (size_t)8192*16*4;
static constexpr size_t OFF_KSRC = OFF_TOPV + (size_t)8192*16*4; // int [8192][16]
static constexpr size_t OFF_A    = OFF_KSRC + (size_t)8192*16*4; // x@Wsrc
static constexpr size_t OFF_B    = OFF_A    + (size_t)8192*128*4; // x@Wdst
static constexpr size_t OFF_V    = OFF_B    + (size_t)8192*128*4; // x@Wlin
static constexpr size_t OFF_H    = OFF_V    + (size_t)8192*128*4; // conv out
static constexpr size_t OFF_HD   = OFF_H    + (size_t)8192*128*4; // after down
static constexpr size_t OFF_Y    = OFF_HD   + (size_t)8192*128*4; // after pool
static constexpr size_t OFF_ACCX = OFF_Y    + (size_t)8192*128*4; // voxel sums
static constexpr size_t OFF_ACCP = OFF_ACCX + (size_t)8192*128*4; // voxel pos sums
static constexpr size_t OFF_HIST = OFF_ACCP + (size_t)8192*3*4;   // int [8192]
static constexpr size_t OFF_RANK = OFF_HIST + (size_t)8192*4;     // int [8192]
static constexpr size_t OFF_UCNT = OFF_RANK + (size_t)8192*4;     // int [8192]
static constexpr size_t OFF_VID  = OFF_UCNT + (size_t)8192*4;     // int [8192]
static constexpr size_t OFF_META = OFF_VID  + (size_t)8192*4;     // posmin f[3] @0, nv i[3] @16B, U i @32B

// ---------------- kernels ----------------

// pos column-min and voxel-grid extents (single block, 1024 threads)
__global__ __launch_bounds__(1024) void k_prep(const float* __restrict__ pos,
                                               float* __restrict__ meta_f, int* __restrict__ meta_i){
  __shared__ float red[1024][3];
  __shared__ int   redi[1024][3];
  __shared__ float pmn[3];
  int t = threadIdx.x;
  float mn[3] = {1e30f,1e30f,1e30f};
  for (int n=t; n<NN; n+=1024){
    #pragma unroll
    for (int d=0; d<3; d++) mn[d] = fminf(mn[d], pos[n*3+d]);
  }
  #pragma unroll
  for (int d=0; d<3; d++) red[t][d] = mn[d];
  __syncthreads();
  for (int s=512; s>0; s>>=1){
    if (t < s){ for (int d=0; d<3; d++) red[t][d] = fminf(red[t][d], red[t+s][d]); }
    __syncthreads();
  }
  if (t < 3) pmn[t] = red[0][t];
  __syncthreads();
  int mx[3] = {0,0,0};
  for (int n=t; n<NN; n+=1024){
    #pragma unroll
    for (int d=0; d<3; d++){
      int v = (int)floorf((pos[n*3+d] - pmn[d]) * 2.0f);   // /0.5 == *2 exactly
      mx[d] = max(mx[d], v);
    }
  }
  #pragma unroll
  for (int d=0; d<3; d++) redi[t][d] = mx[d];
  __syncthreads();
  for (int s=512; s>0; s>>=1){
    if (t < s){ for (int d=0; d<3; d++) redi[t][d] = max(redi[t][d], redi[t+s][d]); }
    __syncthreads();
  }
  if (t == 0){
    meta_f[0]=pmn[0]; meta_f[1]=pmn[1]; meta_f[2]=pmn[2];
    meta_i[0]=redi[0][0]+1; meta_i[1]=redi[0][1]+1; meta_i[2]=redi[0][2]+1;
  }
}

// voxel id + histogram + pos squared norms
__global__ __launch_bounds__(256) void k_vid(const float* __restrict__ pos,
                                             const float* __restrict__ meta_f, const int* __restrict__ meta_i,
                                             int* __restrict__ vid, int* __restrict__ hist,
                                             float* __restrict__ sp){
  int n = blockIdx.x*256 + threadIdx.x;
  float p0=pos[n*3], p1=pos[n*3+1], p2=pos[n*3+2];
  sp[n] = p0*p0 + p1*p1 + p2*p2;
  int v0 = (int)floorf((p0-meta_f[0])*2.0f);
  int v1 = (int)floorf((p1-meta_f[1])*2.0f);
  int v2 = (int)floorf((p2-meta_f[2])*2.0f);
  int id = (v0*meta_i[1] + v1)*meta_i[2] + v2;
  vid[n] = id;
  atomicAdd(&hist[id], 1);
}

// emb = relu(x@Wg1+bg1)@Wg2+bg2 + u*0.001 ; se = |emb|^2 ; embT[10][N]
__global__ __launch_bounds__(64) void k_emb(const float* __restrict__ x,
    const float* __restrict__ Wg1, const float* __restrict__ bg1,
    const float* __restrict__ Wg2, const float* __restrict__ bg2,
    u32 ka, u32 kb, float* __restrict__ embT, float* __restrict__ se){
  int i = blockIdx.x; int t = threadIdx.x;
  __shared__ float xs[64], hs[64], esq[10];
  xs[t] = x[i*64+t];
  __syncthreads();
  float a = bg1[t];
  for (int k=0; k<64; k++) a += xs[k]*Wg1[k*64+t];
  hs[t] = fmaxf(a, 0.0f);
  __syncthreads();
  if (t < 10){
    float e = bg2[t];
    for (int k=0; k<64; k++) e += hs[k]*Wg2[k*10+t];
    e += u01(rbits(ka, kb, (u32)(i*10+t), 81920u)) * 0.001f;
    embT[t*NN + i] = e;
    esq[t] = e*e;
  }
  __syncthreads();
  if (t == 0){
    float ssum = 0.0f;
    #pragma unroll
    for (int d=0; d<10; d++) ssum += esq[d];
    se[i] = ssum;
  }
}

// KNN: top-16 smallest d2 per row (diag excluded), ties -> lower index
__global__ __launch_bounds__(64) void k_knn(const float* __restrict__ pos, const float* __restrict__ sp,
                                            int* __restrict__ knn_src){
  int i = blockIdx.x; int l = threadIdx.x;
  float pi0=pos[i*3], pi1=pos[i*3+1], pi2=pos[i*3+2];
  float spi = sp[i];
  float lv[16]; int lj[16];
  #pragma unroll
  for (int s=0; s<16; s++){ lv[s]=1e30f; lj[s]=0x7fffffff; }
  for (int tt=0; tt<128; tt++){
    int j = l + 64*tt;
    if (j == i) continue;
    float d = spi + sp[j] - 2.0f*(pi0*pos[j*3] + pi1*pos[j*3+1] + pi2*pos[j*3+2]);
    d = fmaxf(d, 0.0f);
    if (d < lv[15]){
      lv[15]=d; lj[15]=j;
      #pragma unroll
      for (int s=15; s>0; s--){
        if (lv[s] < lv[s-1]){ float tv=lv[s]; lv[s]=lv[s-1]; lv[s-1]=tv; int tj=lj[s]; lj[s]=lj[s-1]; lj[s-1]=tj; }
      }
    }
  }
  for (int r=0; r<16; r++){
    float bv = lv[0]; int bj = lj[0];
    #pragma unroll
    for (int off=32; off>=1; off>>=1){
      float ov = __shfl_xor(bv, off);
      int   oj = __shfl_xor(bj, off);
      if (ov < bv || (ov == bv && oj < bj)){ bv = ov; bj = oj; }
    }
    if (l == 0) knn_src[i*16+r] = bj;
    if (lj[0] == bj){
      #pragma unroll
      for (int s=0; s<15; s++){ lv[s]=lv[s+1]; lj[s]=lj[s+1]; }
      lv[15]=1e30f; lj[15]=0x7fffffff;
    }
  }
}

// column softmax stats over a 256-row chunk (online max/sum)
__global__ __launch_bounds__(256) void k_colstats(const float* __restrict__ embT, const float* __restrict__ se,
                                                  u32 ka, u32 kb,
                                                  float* __restrict__ pmax, float* __restrict__ psum){
  __shared__ float eS[256][10];
  __shared__ float sS[256];
  int t = threadIdx.x;
  int j = blockIdx.x*256 + t;
  int i0 = blockIdx.y*256;
  for (int idx=t; idx<2560; idx+=256){
    int d = idx >> 8;         // /256
    int r = idx & 255;
    eS[r][d] = embT[d*NN + i0 + r];
  }
  sS[t] = se[i0 + t];
  __syncthreads();
  float ej[10];
  #pragma unroll
  for (int d=0; d<10; d++) ej[d] = embT[d*NN + j];
  float sej = se[j];
  float m = -1e30f, s = 0.0f;
  for (int r=0; r<256; r++){
    u32 p = (u32)(i0+r)*8192u + (u32)j;
    float z = z_val(eS[r], sS[r], ej, sej, rbits(ka, kb, p, 67108864u));
    if (z > m){ s = s*__expf(m - z) + 1.0f; m = z; }
    else      { s += __expf(z - m); }
  }
  pmax[blockIdx.y*NN + j] = m;
  psum[blockIdx.y*NN + j] = s;
}

// combine chunk stats; store colmax and RECIPROCAL colsum
__global__ __launch_bounds__(256) void k_colcombine(const float* __restrict__ pmax, const float* __restrict__ psum,
                                                    float* __restrict__ colmax, float* __restrict__ icolsum){
  int j = blockIdx.x*256 + threadIdx.x;
  float M = -1e30f;
  for (int c=0; c<32; c++) M = fmaxf(M, pmax[c*NN + j]);
  float S = 0.0f;
  for (int c=0; c<32; c++) S += psum[c*NN + j] * __expf(pmax[c*NN + j] - M);
  colmax[j] = M; icolsum[j] = 1.0f / S;
}

// per-row top-16 of probs = exp(z - colmax[j]) * icolsum[j]
__global__ __launch_bounds__(64) void k_rowtopk(const float* __restrict__ embT, const float* __restrict__ se,
    const float* __restrict__ colmax, const float* __restrict__ icolsum,
    u32 ka, u32 kb, int* __restrict__ soft_src, float* __restrict__ top_v){
  int i = blockIdx.x; int l = threadIdx.x;
  float ei[10];
  #pragma unroll
  for (int d=0; d<10; d++) ei[d] = embT[d*NN + i];
  float sei = se[i];
  float lv[16]; int lj[16];
  #pragma unroll
  for (int s=0; s<16; s++){ lv[s]=-1e30f; lj[s]=0x7fffffff; }
  for (int tt=0; tt<128; tt++){
    int j = l + 64*tt;
    float ej[10];
    #pragma unroll
    for (int d=0; d<10; d++) ej[d] = embT[d*NN + j];
    u32 p = (u32)i*8192u + (u32)j;
    float z = z_val(ei, sei, ej, se[j], rbits(ka, kb, p, 67108864u));
    float pr = __expf(z - colmax[j]) * icolsum[j];
    if (pr > lv[15]){
      lv[15]=pr; lj[15]=j;
      #pragma unroll
      for (int s=15; s>0; s--){
        if (lv[s] > lv[s-1]){ float tv=lv[s]; lv[s]=lv[s-1]; lv[s-1]=tv; int tj=lj[s]; lj[s]=lj[s-1]; lj[s-1]=tj; }
      }
    }
  }
  for (int r=0; r<16; r++){
    float bv = lv[0]; int bj = lj[0];
    #pragma unroll
    for (int off=32; off>=1; off>>=1){
      float ov = __shfl_xor(bv, off);
      int   oj = __shfl_xor(bj, off);
      if (ov > bv || (ov == bv && oj < bj)){ bv = ov; bj = oj; }
    }
    if (l == 0){ soft_src[i*16+r] = bj; top_v[i*16+r] = bv; }
    if (lj[0] == bj){
      #pragma unroll
      for (int s=0; s<15; s++){ lv[s]=lv[s+1]; lj[s]=lj[s+1]; }
      lv[15]=-1e30f; lj[15]=0x7fffffff;
    }
  }
}

// A = x@Wsrc, B = x@Wdst, V = x@Wlin  (8 rows per block)
__global__ __launch_bounds__(128) void k_xw(const float* __restrict__ x,
    const float* __restrict__ Wsrc, const float* __restrict__ Wdst, const float* __restrict__ Wlin,
    float* __restrict__ A, float* __restrict__ B, float* __restrict__ V){
  int g0 = blockIdx.x*8; int c = threadIdx.x;
  __shared__ float xs[8][64];
  for (int idx=c; idx<512; idx+=128) xs[idx>>6][idx&63] = x[(g0 + (idx>>6))*64 + (idx&63)];
  __syncthreads();
  float aA[8], aB[8], aV[8];
  #pragma unroll
  for (int g=0; g<8; g++){ aA[g]=0.0f; aB[g]=0.0f; aV[g]=0.0f; }
  for (int k=0; k<64; k++){
    float ws=Wsrc[k*128+c], wd=Wdst[k*128+c], wl=Wlin[k*128+c];
    #pragma unroll
    for (int g=0; g<8; g++){
      float xv = xs[g][k];
      aA[g] += xv*ws; aB[g] += xv*wd; aV[g] += xv*wl;
    }
  }
  #pragma unroll
  for (int g=0; g<8; g++){
    A[(g0+g)*128+c]=aA[g]; B[(g0+g)*128+c]=aB[g]; V[(g0+g)*128+c]=aV[g];
  }
}

// 2-column GEMM: acc{0,1}[e] = bias + sum_k ein[e][k] * W[k][c{0,1}]
#define GEMM2(WPTR, BPTR)                                                  \
  {                                                                        \
    float bb0 = (BPTR)[c0], bb1 = (BPTR)[c1];                              \
    _Pragma("unroll")                                                      \
    for (int e=0; e<32; e++){ a0[e] = bb0; a1[e] = bb1; }                  \
    for (int k=0; k<128; k+=4){                                            \
      float wa0=(WPTR)[(k+0)*128+c0], wa1=(WPTR)[(k+1)*128+c0];            \
      float wa2=(WPTR)[(k+2)*128+c0], wa3=(WPTR)[(k+3)*128+c0];            \
      float wb0=(WPTR)[(k+0)*128+c1], wb1=(WPTR)[(k+1)*128+c1];            \
      float wb2=(WPTR)[(k+2)*128+c1], wb3=(WPTR)[(k+3)*128+c1];            \
      _Pragma("unroll")                                                    \
      for (int e=0; e<32; e++){                                            \
        const float4 ev = *(const float4*)(&ein[e][k]);                    \
        a0[e] += ev.x*wa0 + ev.y*wa1 + ev.z*wa2 + ev.w*wa3;                \
        a1[e] += ev.x*wb0 + ev.y*wb1 + ev.z*wb2 + ev.w*wb3;                \
      }                                                                    \
    }                                                                      \
  }

// PointTransformerConv: per-target fused (32 edges), vector attention.
// 64 threads, 2 output columns per thread -> 2x FMA per LDS b128 read.
__global__ __launch_bounds__(64) void k_edge(const float* __restrict__ pos,
    const int* __restrict__ soft_src, const float* __restrict__ top_v, const int* __restrict__ knn_src,
    const float* __restrict__ A, const float* __restrict__ B, const float* __restrict__ V,
    const float* __restrict__ Wp1, const float* __restrict__ bp1,
    const float* __restrict__ Wp2, const float* __restrict__ bp2,
    const float* __restrict__ Wa1, const float* __restrict__ ba1,
    const float* __restrict__ Wa2, const float* __restrict__ ba2,
    float* __restrict__ h){
  int i = blockIdx.x; int l = threadIdx.x;
  const int c0 = l, c1 = l + 64;
  __shared__ float ein[32][128];
  __shared__ int   ssrc[32];
  __shared__ float sw[32];
  __shared__ float sdp[32][3];
  if (l < 32){
    int s; float w;
    if (l < 16){ s = soft_src[i*16+l]; w = top_v[i*16+l]; }
    else       { s = knn_src[i*16+(l-16)]; w = 1.0f; }
    ssrc[l]=s; sw[l]=w;
    sdp[l][0]=pos[i*3]-pos[s*3]; sdp[l][1]=pos[i*3+1]-pos[s*3+1]; sdp[l][2]=pos[i*3+2]-pos[s*3+2];
  }
  __syncthreads();
  // ph = relu(dpos @ Wp1 + bp1)
  {
    float pa0=Wp1[c0], pa1=Wp1[128+c0], pa2=Wp1[256+c0], pb=bp1[c0];
    float qa0=Wp1[c1], qa1=Wp1[128+c1], qa2=Wp1[256+c1], qb=bp1[c1];
    #pragma unroll
    for (int e=0; e<32; e++){
      float e0=sdp[e][0], e1=sdp[e][1], e2=sdp[e][2];
      ein[e][c0] = fmaxf(e0*pa0 + e1*pa1 + e2*pa2 + pb, 0.0f);
      ein[e][c1] = fmaxf(e0*qa0 + e1*qa1 + e2*qa2 + qb, 0.0f);
    }
  }
  __syncthreads();
  float a0[32], a1[32];
  // delta = ph @ Wp2 + bp2
  GEMM2(Wp2, bp2);
  __syncthreads();
  float d0[32], d1[32];
  #pragma unroll
  for (int e=0; e<32; e++){ d0[e] = a0[e]; d1[e] = a1[e]; }
  // q = B[i] - A[src] + delta
  float bi0 = B[i*128+c0], bi1 = B[i*128+c1];
  #pragma unroll
  for (int e=0; e<32; e++){
    int s = ssrc[e];
    ein[e][c0] = bi0 - A[s*128+c0] + d0[e];
    ein[e][c1] = bi1 - A[s*128+c1] + d1[e];
  }
  __syncthreads();
  // ah = relu(q @ Wa1 + ba1)
  GEMM2(Wa1, ba1);
  __syncthreads();
  #pragma unroll
  for (int e=0; e<32; e++){ ein[e][c0] = fmaxf(a0[e], 0.0f); ein[e][c1] = fmaxf(a1[e], 0.0f); }
  __syncthreads();
  // logits = ah @ Wa2 + ba2
  GEMM2(Wa2, ba2);
  // per-channel softmax over 32 edges, aggregate msg = attn*(V[src]+delta)*w
  float m0 = a0[0], m1 = a1[0];
  #pragma unroll
  for (int e=1; e<32; e++){ m0 = fmaxf(m0, a0[e]); m1 = fmaxf(m1, a1[e]); }
  float s0=0.0f, h0=0.0f, s1=0.0f, h1=0.0f;
  #pragma unroll
  for (int e=0; e<32; e++){
    int s = ssrc[e]; float w = sw[e];
    float p0 = __expf(a0[e] - m0);
    float p1 = __expf(a1[e] - m1);
    s0 += p0; s1 += p1;
    h0 += p0 * (V[s*128+c0] + d0[e]) * w;
    h1 += p1 * (V[s*128+c1] + d1[e]) * w;
  }
  h[i*128+c0] = h0 / (s0 + 1e-16f);
  h[i*128+c1] = h1 / (s1 + 1e-16f);
}

// hd = relu(h @ Wd + bd)
__global__ __launch_bounds__(128) void k_down(const float* __restrict__ h,
    const float* __restrict__ Wd, const float* __restrict__ bd, float* __restrict__ hd){
  int g0 = blockIdx.x*8; int c = threadIdx.x;
  __shared__ float hs[8][128];
  for (int idx=c; idx<1024; idx+=128) hs[idx>>7][idx&127] = h[(g0 + (idx>>7))*128 + (idx&127)];
  __syncthreads();
  float acc[8]; float b = bd[c];
  #pragma unroll
  for (int g=0; g<8; g++) acc[g] = b;
  for (int k=0; k<128; k+=4){
    float w0=Wd[(k+0)*128+c], w1=Wd[(k+1)*128+c], w2=Wd[(k+2)*128+c], w3=Wd[(k+3)*128+c];
    #pragma unroll
    for (int g=0; g<8; g++){
      const float4 ev = *(const float4*)(&hs[g][k]);
      acc[g] += ev.x*w0 + ev.y*w1 + ev.z*w2 + ev.w*w3;
    }
  }
  #pragma unroll
  for (int g=0; g<8; g++) hd[(g0+g)*128+c] = fmaxf(acc[g], 0.0f);
}

// y = max(hd[i], max over 32 neighbors hd[src])
__global__ __launch_bounds__(128) void k_pool(const float* __restrict__ hd,
    const int* __restrict__ soft_src, const int* __restrict__ knn_src, float* __restrict__ y){
  int i = blockIdx.x; int c = threadIdx.x;
  __shared__ int ss[32];
  if (c < 16) ss[c] = soft_src[i*16+c];
  else if (c < 32) ss[c] = knn_src[i*16+(c-16)];
  __syncthreads();
  float p = hd[i*128+c];
  for (int e=0; e<32; e++) p = fmaxf(p, hd[ss[e]*128+c]);
  y[i*128+c] = p;
}

// ranks = sorted-unique inverse (count of nonzero bins with smaller vid)
__global__ __launch_bounds__(256) void k_scan(const int* __restrict__ hist,
    int* __restrict__ rank, int* __restrict__ ucnt, int* __restrict__ Uo){
  __shared__ int part[256];
  int t = threadIdx.x;
  int base = t*32;
  int cnt = 0;
  for (int b=0; b<32; b++) cnt += (hist[base+b] > 0);
  part[t] = cnt;
  __syncthreads();
  if (t == 0){
    int run = 0;
    for (int q=0; q<256; q++){ int v = part[q]; part[q] = run; run += v; }
    Uo[0] = run;
  }
  __syncthreads();
  int run = part[t];
  for (int b=0; b<32; b++){
    int bin = base + b;
    rank[bin] = run;
    int hv = hist[bin];
    if (hv > 0){ ucnt[run] = hv; run++; }
  }
}

__global__ __launch_bounds__(128) void k_agg(const float* __restrict__ y, const float* __restrict__ pos,
    const int* __restrict__ vid, const int* __restrict__ rank,
    float* __restrict__ accx, float* __restrict__ accp){
  int n = blockIdx.x; int c = threadIdx.x;
  int r = rank[vid[n]];
  atomicAdd(&accx[r*128+c], y[n*128+c]);
  if (c < 3) atomicAdd(&accp[r*3+c], pos[n*3+c]);
}

__global__ __launch_bounds__(128) void k_final(const float* __restrict__ accx, const float* __restrict__ accp,
    const int* __restrict__ ucnt, const int* __restrict__ Uo, float* __restrict__ out){
  int r = blockIdx.x; int c = threadIdx.x;
  int u = Uo[0];
  float cnt = (r < u) ? (float)ucnt[r] : 0.0f;
  float den = fmaxf(cnt, 1.0f);
  out[r*128+c] = (r < u) ? accx[r*128+c]/den : 0.0f;
  if (c < 3) out[(size_t)NN*128 + r*3 + c] = (r < u) ? accp[r*3+c]/den : 0.0f;
  if (c == 0) out[(size_t)NN*128 + (size_t)NN*3 + r] = cnt;
}

// ---------------- launcher ----------------
extern "C" void kernel_launch(void* const* d_in, const int* in_sizes, int n_in,
                              void* d_out, int out_size, void* d_ws, size_t ws_size,
                              hipStream_t stream){
  (void)in_sizes; (void)n_in; (void)out_size; (void)ws_size;
  const float* x    = (const float*)d_in[0];
  const float* pos  = (const float*)d_in[1];
  const float* Wg1  = (const float*)d_in[2];
  const float* bg1  = (const float*)d_in[3];
  const float* Wg2  = (const float*)d_in[4];
  const float* bg2  = (const float*)d_in[5];
  const float* Wlin = (const float*)d_in[6];
  const float* Wsrc = (const float*)d_in[7];
  const float* Wdst = (const float*)d_in[8];
  const float* Wp1  = (const float*)d_in[9];
  const float* bp1  = (const float*)d_in[10];
  const float* Wp2  = (const float*)d_in[11];
  const float* bp2  = (const float*)d_in[12];
  const float* Wa1  = (const float*)d_in[13];
  const float* ba1  = (const float*)d_in[14];
  const float* Wa2  = (const float*)d_in[15];
  const float* ba2  = (const float*)d_in[16];
  const float* Wd   = (const float*)d_in[17];
  const float* bd   = (const float*)d_in[18];

  char* ws = (char*)d_ws;
  float* embT   = (float*)(ws + OFF_EMBT);
  float* se     = (float*)(ws + OFF_SE);
  float* sp     = (float*)(ws + OFF_SP);
  float* colmax = (float*)(ws + OFF_CMAX);
  float* icolsum= (float*)(ws + OFF_CSUM);
  float* pmax   = (float*)(ws + OFF_PMAX);
  float* psum   = (float*)(ws + OFF_PSUM);
  int*   ssrc   = (int*)  (ws + OFF_SSRC);
  float* topv   = (float*)(ws + OFF_TOPV);
  int*   ksrc   = (int*)  (ws + OFF_KSRC);
  float* A      = (float*)(ws + OFF_A);
  float* B      = (float*)(ws + OFF_B);
  float* V      = (float*)(ws + OFF_V);
  float* h      = (float*)(ws + OFF_H);
  float* hd     = (float*)(ws + OFF_HD);
  float* y      = (float*)(ws + OFF_Y);
  float* accx   = (float*)(ws + OFF_ACCX);
  float* accp   = (float*)(ws + OFF_ACCP);
  int*   hist   = (int*)  (ws + OFF_HIST);
  int*   rank   = (int*)  (ws + OFF_RANK);
  int*   ucnt   = (int*)  (ws + OFF_UCNT);
  int*   vid    = (int*)  (ws + OFF_VID);
  float* meta_f = (float*)(ws + OFF_META);
  int*   meta_i = (int*)  (ws + OFF_META + 16);
  int*   Uo     = (int*)  (ws + OFF_META + 32);

  // rk = jax.random.split(jax.random.key(42), 2)  -- host threefry
  u32 rk0a, rk0b, rk1a, rk1b;
#if PARTITIONABLE
  tf2x32(0u, 42u, 0u, 0u, rk0a, rk0b);   // foldlike split: key_j = threefry(key, (0, j))
  tf2x32(0u, 42u, 0u, 1u, rk1a, rk1b);
#else
  { u32 l0o0,l0o1,l1o0,l1o1;
    tf2x32(0u,42u, 0u,2u, l0o0,l0o1);
    tf2x32(0u,42u, 1u,3u, l1o0,l1o1);
    rk0a=l0o0; rk0b=l1o0; rk1a=l0o1; rk1b=l1o1; }
#endif

  hipMemsetAsync(hist, 0, 8192*4, stream);
  hipMemsetAsync(accx, 0, (size_t)8192*128*4, stream);
  hipMemsetAsync(accp, 0, (size_t)8192*3*4, stream);

  k_prep<<<1, 1024, 0, stream>>>(pos, meta_f, meta_i);
  k_vid<<<32, 256, 0, stream>>>(pos, meta_f, meta_i, vid, hist, sp);
  k_emb<<<8192, 64, 0, stream>>>(x, Wg1, bg1, Wg2, bg2, rk0a, rk0b, embT, se);
  k_knn<<<8192, 64, 0, stream>>>(pos, sp, ksrc);
  k_colstats<<<dim3(32,32), 256, 0, stream>>>(embT, se, rk1a, rk1b, pmax, psum);
  k_colcombine<<<32, 256, 0, stream>>>(pmax, psum, colmax, icolsum);
  k_rowtopk<<<8192, 64, 0, stream>>>(embT, se, colmax, icolsum, rk1a, rk1b, ssrc, topv);
  k_xw<<<1024, 128, 0, stream>>>(x, Wsrc, Wdst, Wlin, A, B, V);
  k_edge<<<8192, 64, 0, stream>>>(pos, ssrc, topv, ksrc, A, B, V,
                                  Wp1, bp1, Wp2, bp2, Wa1, ba1, Wa2, ba2, h);
  k_down<<<1024, 128, 0, stream>>>(h, Wd, bd, hd);
  k_pool<<<8192, 128, 0, stream>>>(hd, ssrc, ksrc, y);
  k_scan<<<1, 256, 0, stream>>>(hist, rank, ucnt, Uo);
  k_agg<<<8192, 128, 0, stream>>>(y, pos, vid, rank, accx, accp);
  k_final<<<8192, 128, 0, stream>>>(accx, accp, ucnt, Uo, (float*)d_out);
}